// Round 5
// baseline (239.835 us; speedup 1.0000x reference)
//
#include <hip/hip_runtime.h>
#include <hip/hip_bf16.h>

#define B_  16
#define LQ  2048
#define LS  2048
#define DD  512
#define BQ  128
#define BS  128
#define BK  64
#define NSB (LS / BS)   // 16 s-blocks total
#define NKC (DD / BK)   // 8 k-stages per s-block
#define NSPLIT 4

static_assert(NKC == 8, "stage>>3 math assumes NKC==8");

typedef short bf16x8 __attribute__((ext_vector_type(8)));
typedef float f32x4  __attribute__((ext_vector_type(4)));

// async global->LDS, 16B per lane. LDS dest = wave-uniform base + lane*16.
__device__ __forceinline__ void load_lds16(const void* g, void* l) {
  __builtin_amdgcn_global_load_lds((const __attribute__((address_space(1))) void*)g,
                                   (__attribute__((address_space(3))) void*)l,
                                   16, 0, 0);
}

__device__ __forceinline__ unsigned short f2bf(float f) {
  union { float f; unsigned int u; } v; v.f = f;
  unsigned int r = v.u + 0x7fffu + ((v.u >> 16) & 1u);  // RNE
  return (unsigned short)(r >> 16);
}

// Exact-size grid: blocks [0, nblk) convert Q, [nblk, 2nblk) convert S.
__global__ __launch_bounds__(256) void cvt_kernel(const float* __restrict__ Q,
                                                  const float* __restrict__ S,
                                                  unsigned short* __restrict__ Qw,
                                                  unsigned short* __restrict__ Sw,
                                                  int nblk) {
  int blk = blockIdx.x;
  const float* src; unsigned short* dst;
  if (blk < nblk) { src = Q; dst = Qw; } else { src = S; dst = Sw; blk -= nblk; }
  int i = blk * 256 + threadIdx.x;   // float4 index
  float4 f = ((const float4*)src)[i];
  ushort4 u;
  u.x = f2bf(f.x); u.y = f2bf(f.y); u.z = f2bf(f.z); u.w = f2bf(f.w);
  ((ushort4*)dst)[i] = u;
}

// score[b,q] = sum_s softmax(l)[s]*l[s],  l[s] = Q[b,q,:].S[b,s,:]
// MFMA 16x16x32: A = S-tile (M=s), B = Q-tile^T (N=q) -> C[row=s][col=q]
// C layout: col = lane&15, row = (lane>>4)*4 + reg  [m89/m91]
//
// Round-5 restructure: rounds 2 vs 4 proved barrier-count/phasing is neutral
// at 1 block/CU -- every barrier aligns the whole CU, so LDS (2360cy) + MFMA
// (2480cy) + barriers serialize to the measured 6660 cy/stage. Register wall
// (116 VGPR + 128 AGPR = 244/256) blocks double-fragment pipelining. Fix:
// CROSS-BLOCK overlap (the m97 mechanism) -- 256-thread blocks, BQ=BS=128,
// 4 waves (2s x 2q of 64x64, acc[4][4]=64 AGPR), LDS 64 KiB -> 2 independent
// blocks/CU. Same 8 waves/CU, but block A's barrier stalls overlap block B's
// compute. Regs ~150/wave (headroom for later cvt fusion).
// Kept: counted vmcnt(8), XOR k-chunk swizzle (0 conflicts), chunked XCD
// swizzle (128-lid chunk = 8 S-splits x 512 KB = 4 MB = one XCD L2).
__global__ __launch_bounds__(256, 2) void attn_kernel(const unsigned short* __restrict__ Qw,
                                                      const unsigned short* __restrict__ Sw,
                                                      float* __restrict__ out,
                                                      float* __restrict__ pm,
                                                      float* __restrict__ pse,
                                                      float* __restrict__ psel,
                                                      int nsplit) {
  __shared__ __align__(16) unsigned short sQ[2][BQ * BK];  // 2 x 16 KiB
  __shared__ __align__(16) unsigned short sS[2][BS * BK];  // 2 x 16 KiB

  // --- chunked XCD swizzle (bijective: nwg = 256*nsplit divisible by 8) ---
  const int pid = blockIdx.x + (blockIdx.y << 4) + (blockIdx.z << 8);
  const int nch = (nsplit << 8) >> 3;          // nwg / 8
  const int lid = (pid & 7) * nch + (pid >> 3);
  const int qb  = lid & 15;                    // gridDim.x == 16
  const int b   = (lid >> 4) & 15;             // gridDim.y == 16
  const int spl = lid >> 8;

  const int tid  = threadIdx.x;
  const int w    = tid >> 6;      // 0..3
  const int lane = tid & 63;
  const int h    = w & 1;         // s-half: rows [h*64, h*64+64)
  const int g    = w >> 1;        // q-half: cols [g*64, g*64+64)
  const int col  = lane & 15;
  const int quad = lane >> 4;
  const int c7   = col & 7;

  const int q0 = qb * BQ;
  const unsigned short* Qb = Qw + (size_t)b * LQ * DD;
  const unsigned short* Sb = Sw + (size_t)b * LS * DD;

  float mst[4] = { -INFINITY, -INFINITY, -INFINITY, -INFINITY };
  float se[4]  = { 0.f, 0.f, 0.f, 0.f };
  float sel[4] = { 0.f, 0.f, 0.f, 0.f };

  f32x4 acc[4][4];   // [s-tile][q-tile] = 64 regs
#pragma unroll
  for (int st = 0; st < 4; ++st)
#pragma unroll
    for (int qt = 0; qt < 4; ++qt)
      acc[st][qt] = (f32x4){0.f, 0.f, 0.f, 0.f};

  const int rr = lane >> 3;                 // row within 8-row staging group
  const int cc = ((lane & 7) ^ rr) * 8;     // swizzled global k-chunk

  const int sbs = spl * (NSB / nsplit);
  const int nst = (NSB / nsplit) * NKC;     // flattened stage count (32)

  // each of the 4 waves stages 32 Q-rows and 32 S-rows (4+4 gl_lds)
  auto issue_stage = [&](int t_i, int buf) {
    const int kc = t_i & 7;
    const int sb = sbs + (t_i >> 3);
    const unsigned short* gq = Qb + (size_t)(q0 + w * 32 + rr) * DD + kc * BK + cc;
    const unsigned short* gs = Sb + (size_t)(sb * BS + w * 32 + rr) * DD + kc * BK + cc;
    unsigned short* lq = &sQ[buf][(w * 32) * BK];
    unsigned short* ls = &sS[buf][(w * 32) * BK];
#pragma unroll
    for (int i = 0; i < 4; ++i)
      load_lds16(gq + (size_t)i * 8 * DD, lq + i * 8 * BK);
#pragma unroll
    for (int i = 0; i < 4; ++i)
      load_lds16(gs + (size_t)i * 8 * DD, ls + i * 8 * BK);
  };

  // prologue: stage 0 -> buf 0, drain, sync
  issue_stage(0, 0);
  asm volatile("s_waitcnt vmcnt(0)" ::: "memory");
  __builtin_amdgcn_s_barrier();
  int cur = 0;

#pragma unroll 1
  for (int t = 0; t < nst; ++t) {
    const int tn = t + 1;
    // barrier A: all waves done ds-reading buf[cur^1] -> safe to refill it
    asm volatile("s_waitcnt lgkmcnt(0)" ::: "memory");
    __builtin_amdgcn_s_barrier();
    if (tn < nst) {
      issue_stage(tn, cur ^ 1);
      asm volatile("s_waitcnt vmcnt(8)" ::: "memory");  // stage t landed; t+1 in flight
    } else {
      asm volatile("s_waitcnt vmcnt(0)" ::: "memory");
    }
    // barrier B: stage t (staged by ALL waves) visible in LDS
    __builtin_amdgcn_s_barrier();

    const unsigned short* bq = &sQ[cur][0];
    const unsigned short* bs = &sS[cur][0];
#pragma unroll
    for (int kk = 0; kk < 2; ++kk) {
      const int koff = ((kk * 4 + quad) ^ c7) * 8;
      bf16x8 asv[4], aq[4];
#pragma unroll
      for (int st = 0; st < 4; ++st)
        asv[st] = *(const bf16x8*)&bs[(h * 64 + st * 16 + col) * BK + koff];
#pragma unroll
      for (int qt = 0; qt < 4; ++qt)
        aq[qt] = *(const bf16x8*)&bq[(g * 64 + qt * 16 + col) * BK + koff];
#pragma unroll
      for (int qt = 0; qt < 4; ++qt)
#pragma unroll
        for (int st = 0; st < 4; ++st)
          acc[st][qt] = __builtin_amdgcn_mfma_f32_16x16x32_bf16(asv[st], aq[qt], acc[st][qt], 0, 0, 0);
    }
    cur ^= 1;

    if ((t & (NKC - 1)) == NKC - 1) {
      // online softmax-weighted-mean update over this wave's 64-s half-block
      // (next s-block's first loads already in flight -> overlaps this VALU)
#pragma unroll
      for (int qt = 0; qt < 4; ++qt) {
        float lmax = mst[qt];
#pragma unroll
        for (int st = 0; st < 4; ++st)
#pragma unroll
          for (int r = 0; r < 4; ++r)
            lmax = fmaxf(lmax, acc[st][qt][r]);
        lmax = fmaxf(lmax, __shfl_xor(lmax, 16, 64));
        lmax = fmaxf(lmax, __shfl_xor(lmax, 32, 64));
        float alpha = __expf(mst[qt] - lmax);  // exp(-inf)=0 on first block
        float pe = 0.f, pel = 0.f;
#pragma unroll
        for (int st = 0; st < 4; ++st)
#pragma unroll
          for (int r = 0; r < 4; ++r) {
            float l = acc[st][qt][r];
            float e = __expf(l - lmax);
            pe += e;
            pel = fmaf(e, l, pel);
          }
        pe  += __shfl_xor(pe, 16, 64);  pe  += __shfl_xor(pe, 32, 64);
        pel += __shfl_xor(pel, 16, 64); pel += __shfl_xor(pel, 32, 64);
        se[qt]  = fmaf(se[qt],  alpha, pe);
        sel[qt] = fmaf(sel[qt], alpha, pel);
        mst[qt] = lmax;
#pragma unroll
        for (int st = 0; st < 4; ++st)
          acc[st][qt] = (f32x4){0.f, 0.f, 0.f, 0.f};
      }
    }
  }

  // merge the two s-halves (h=0,1) per q-half via LDS, then write
  __syncthreads();
  float* red = (float*)&sQ[0][0];   // 3*256 floats = 3 KiB, sQ no longer needed
  if (quad == 0) {
#pragma unroll
    for (int qt = 0; qt < 4; ++qt) {
      int qq = g * 64 + qt * 16 + col;           // 0..127
      red[h * 128 + qq]       = mst[qt];
      red[256 + h * 128 + qq] = se[qt];
      red[512 + h * 128 + qq] = sel[qt];
    }
  }
  __syncthreads();
  if (h == 0 && quad == 0) {
#pragma unroll
    for (int qt = 0; qt < 4; ++qt) {
      int qq = g * 64 + qt * 16 + col;
      float m0 = red[qq],       m1 = red[128 + qq];
      float M  = fmaxf(m0, m1);
      float a0 = __expf(m0 - M), a1 = __expf(m1 - M);
      float SE  = red[256 + qq] * a0 + red[256 + 128 + qq] * a1;
      float SEL = red[512 + qq] * a0 + red[512 + 128 + qq] * a1;
      size_t qi = (size_t)b * LQ + q0 + qq;
      if (nsplit == 1) {
        out[qi] = SEL / SE;
      } else {
        pm[qi * NSPLIT + spl]   = M;
        pse[qi * NSPLIT + spl]  = SE;
        psel[qi * NSPLIT + spl] = SEL;
      }
    }
  }
}

__global__ __launch_bounds__(256) void combine_kernel(const float* __restrict__ pm,
                                                      const float* __restrict__ pse,
                                                      const float* __restrict__ psel,
                                                      float* __restrict__ out) {
  int i = blockIdx.x * blockDim.x + threadIdx.x;
  if (i >= B_ * LQ) return;
  float M = -INFINITY;
#pragma unroll
  for (int s = 0; s < NSPLIT; ++s) M = fmaxf(M, pm[i * NSPLIT + s]);
  float SE = 0.f, SEL = 0.f;
#pragma unroll
  for (int s = 0; s < NSPLIT; ++s) {
    float a = __expf(pm[i * NSPLIT + s] - M);
    SE  = fmaf(pse[i * NSPLIT + s],  a, SE);
    SEL = fmaf(psel[i * NSPLIT + s], a, SEL);
  }
  out[i] = SEL / SE;
}

// fp32 fallback (correctness insurance if ws too small)
__global__ __launch_bounds__(256) void fallback_kernel(const float* __restrict__ Q,
                                                       const float* __restrict__ S,
                                                       float* __restrict__ out) {
  __shared__ float qv[DD];
  __shared__ float red[256];
  const int b = blockIdx.y, qi = blockIdx.x, tid = threadIdx.x;
  const float* qrow = Q + ((size_t)b * LQ + qi) * DD;
  for (int d = tid; d < DD; d += 256) qv[d] = qrow[d];
  __syncthreads();
  const float* Sb = S + (size_t)b * LS * DD;
  float m = -INFINITY, se = 0.f, sel = 0.f;
  for (int s = tid; s < LS; s += 256) {
    const float* srow = Sb + (size_t)s * DD;
    float dot = 0.f;
    for (int d = 0; d < DD; ++d) dot = fmaf(qv[d], srow[d], dot);
    float mn = fmaxf(m, dot);
    float a = __expf(m - mn);
    float e = __expf(dot - mn);
    se  = se * a + e;
    sel = sel * a + e * dot;
    m = mn;
  }
  red[tid] = m; __syncthreads();
  for (int o = 128; o > 0; o >>= 1) { if (tid < o) red[tid] = fmaxf(red[tid], red[tid + o]); __syncthreads(); }
  float M = red[0]; __syncthreads();
  float a = __expf(m - M); se *= a; sel *= a;
  red[tid] = se; __syncthreads();
  for (int o = 128; o > 0; o >>= 1) { if (tid < o) red[tid] += red[tid + o]; __syncthreads(); }
  float SE = red[0]; __syncthreads();
  red[tid] = sel; __syncthreads();
  for (int o = 128; o > 0; o >>= 1) { if (tid < o) red[tid] += red[tid + o]; __syncthreads(); }
  float SEL = red[0];
  if (tid == 0) out[(size_t)b * LQ + qi] = SEL / SE;
}

extern "C" void kernel_launch(void* const* d_in, const int* in_sizes, int n_in,
                              void* d_out, int out_size, void* d_ws, size_t ws_size,
                              hipStream_t stream) {
  const float* Q = (const float*)d_in[0];
  const float* S = (const float*)d_in[1];
  float* out = (float*)d_out;
  const size_t nelem = (size_t)B_ * LQ * DD;                    // 16.78M / tensor
  const size_t need_base  = 2 * nelem * sizeof(unsigned short); // 67 MiB
  const size_t part_elems = (size_t)B_ * LQ * NSPLIT;
  const size_t need_split = need_base + 3 * part_elems * sizeof(float);

  if (ws_size >= need_base) {
    unsigned short* Qw = (unsigned short*)d_ws;
    unsigned short* Sw = Qw + nelem;
    int nblk = (int)(nelem / 4 / 256);   // exact: nelem divisible by 1024
    cvt_kernel<<<2 * nblk, 256, 0, stream>>>(Q, S, Qw, Sw, nblk);
    if (ws_size >= need_split) {
      float* pm   = (float*)(Sw + nelem);
      float* pse  = pm + part_elems;
      float* psel = pse + part_elems;
      attn_kernel<<<dim3(LQ / BQ, B_, NSPLIT), 256, 0, stream>>>(Qw, Sw, out, pm, pse, psel, NSPLIT);
      combine_kernel<<<(B_ * LQ + 255) / 256, 256, 0, stream>>>(pm, pse, psel, out);
    } else {
      attn_kernel<<<dim3(LQ / BQ, B_, 1), 256, 0, stream>>>(Qw, Sw, out, nullptr, nullptr, nullptr, 1);
    }
  } else {
    fallback_kernel<<<dim3(LQ, B_), 256, 0, stream>>>(Q, S, out);
  }
}

// Round 6
// 217.725 us; speedup vs baseline: 1.1015x; 1.1015x over previous
//
#include <hip/hip_runtime.h>
#include <hip/hip_bf16.h>

#define B_  16
#define LQ  2048
#define LS  2048
#define DD  512
#define BQ  256
#define BS  256
#define BK  64
#define NSB (LS / BS)   // 8 s-blocks total
#define NKC (DD / BK)   // 8 k-stages per s-block
#define NSPLIT 4

static_assert(NKC == 8, "stage>>3 math assumes NKC==8");

typedef short bf16x8 __attribute__((ext_vector_type(8)));
typedef float f32x4  __attribute__((ext_vector_type(4)));

// async global->LDS, 16B per lane. LDS dest = wave-uniform base + lane*16.
__device__ __forceinline__ void load_lds16(const void* g, void* l) {
  __builtin_amdgcn_global_load_lds((const __attribute__((address_space(1))) void*)g,
                                   (__attribute__((address_space(3))) void*)l,
                                   16, 0, 0);
}

__device__ __forceinline__ unsigned short f2bf(float f) {
  union { float f; unsigned int u; } v; v.f = f;
  unsigned int r = v.u + 0x7fffu + ((v.u >> 16) & 1u);  // RNE
  return (unsigned short)(r >> 16);
}

// Grid-stride cvt: 2048 blocks (first half Q, second half S), 16 iters each.
__global__ __launch_bounds__(256) void cvt_kernel(const float* __restrict__ Q,
                                                  const float* __restrict__ S,
                                                  unsigned short* __restrict__ Qw,
                                                  unsigned short* __restrict__ Sw) {
  const int half = gridDim.x >> 1;
  int blk = blockIdx.x;
  const float* src; unsigned short* dst;
  if (blk < half) { src = Q; dst = Qw; } else { src = S; dst = Sw; blk -= half; }
  const size_t n4 = (size_t)B_ * LQ * DD / 4;
  const size_t stride = (size_t)half * 256;
  for (size_t i = (size_t)blk * 256 + threadIdx.x; i < n4; i += stride) {
    float4 f = ((const float4*)src)[i];
    ushort4 u;
    u.x = f2bf(f.x); u.y = f2bf(f.y); u.z = f2bf(f.z); u.w = f2bf(f.w);
    ((ushort4*)dst)[i] = u;
  }
}

// score[b,q] = sum_s softmax(l)[s]*l[s],  l[s] = Q[b,q,:].S[b,s,:]
// MFMA 16x16x32: A = S-tile (M=s), B = Q-tile^T (N=q) -> C[row=s][col=q]
// C layout: col = lane&15, row = (lane>>4)*4 + reg  [m89/m91]
//
// Round-6 changes on the proven R2 structure (88.8 us):
//  (1) L2-locality lid decode: lid = (b<<5) | (spl<<3) | qb. One XCD's 64-lid
//      chunk = ONE or TWO b values -> concurrent working set per XCD =
//      Q-tile 2 MB + 4 S-splits x 0.5 MB = 4 MB = L2-resident (old decode had
//      8 b's = 20 MB -> LLC-served staging, the suspected per-stage stall).
//  (2) ONE barrier per stage: issue prefetch at stage top (safe: the target
//      buffer's readers retired before the barrier we just crossed), vmcnt(0)
//      at stage end -- in-flight window = whole MFMA phase (~2500 cy >> 900).
//  (3) cvt grid-stride (2048 blocks).
__global__ __launch_bounds__(512, 2) void attn_kernel(const unsigned short* __restrict__ Qw,
                                                      const unsigned short* __restrict__ Sw,
                                                      float* __restrict__ out,
                                                      float* __restrict__ pm,
                                                      float* __restrict__ pse,
                                                      float* __restrict__ psel,
                                                      int nsplit) {
  __shared__ __align__(16) unsigned short sQ[2][BQ * BK];  // 2 x 32 KiB
  __shared__ __align__(16) unsigned short sS[2][BS * BK];  // 2 x 32 KiB

  // --- chunked XCD swizzle (bijective: nwg = 128*nsplit divisible by 8) ---
  const int pid = blockIdx.x + (blockIdx.y << 3) + (blockIdx.z << 7);
  const int nch = (nsplit << 7) >> 3;          // nwg / 8
  const int lid = (pid & 7) * nch + (pid >> 3);
  // locality decode: qb fastest, then spl, then b
  const int qb   = lid & 7;                    // gridDim.x == 8
  const int rest = lid >> 3;
  const int spl  = rest & (nsplit - 1);        // nsplit in {1,4}
  const int b    = rest >> (nsplit == 4 ? 2 : 0);

  const int tid  = threadIdx.x;
  const int w    = tid >> 6;      // 0..7
  const int lane = tid & 63;
  const int h    = w & 1;         // s-half: rows [h*128, h*128+128)
  const int g    = w >> 1;        // q-quarter: cols [g*64, g*64+64)
  const int col  = lane & 15;
  const int quad = lane >> 4;
  const int c7   = col & 7;

  const int q0 = qb * BQ;
  const unsigned short* Qb = Qw + (size_t)b * LQ * DD;
  const unsigned short* Sb = Sw + (size_t)b * LS * DD;

  float mst[4] = { -INFINITY, -INFINITY, -INFINITY, -INFINITY };
  float se[4]  = { 0.f, 0.f, 0.f, 0.f };
  float sel[4] = { 0.f, 0.f, 0.f, 0.f };

  f32x4 acc[8][4];   // [s-tile][q-tile] = 128 regs
#pragma unroll
  for (int st = 0; st < 8; ++st)
#pragma unroll
    for (int qt = 0; qt < 4; ++qt)
      acc[st][qt] = (f32x4){0.f, 0.f, 0.f, 0.f};

  const int rr = lane >> 3;                 // row within 8-row staging group
  const int cc = ((lane & 7) ^ rr) * 8;     // swizzled global k-chunk

  const int sbs = spl * (NSB / nsplit);
  const int nst = (NSB / nsplit) * NKC;     // flattened stage count

  // waves 0..3 stage Q rows [w*64, w*64+64); waves 4..7 stage S likewise.
  auto issue_stage = [&](int t_i, int buf) {
    const int kc = t_i & 7;
    if (w < 4) {
      const unsigned short* gp = Qb + (size_t)(q0 + w * 64 + rr) * DD + kc * BK + cc;
      unsigned short* lp = &sQ[buf][(w * 64) * BK];
#pragma unroll
      for (int i = 0; i < 8; ++i)
        load_lds16(gp + (size_t)i * 8 * DD, lp + i * 8 * BK);
    } else {
      const int sb = sbs + (t_i >> 3);
      const unsigned short* gp = Sb + (size_t)(sb * BS + (w - 4) * 64 + rr) * DD + kc * BK + cc;
      unsigned short* lp = &sS[buf][((w - 4) * 64) * BK];
#pragma unroll
      for (int i = 0; i < 8; ++i)
        load_lds16(gp + (size_t)i * 8 * DD, lp + i * 8 * BK);
    }
  };

  // prologue: stage 0 -> buf 0, drain, sync
  issue_stage(0, 0);
  asm volatile("s_waitcnt vmcnt(0)" ::: "memory");
  __builtin_amdgcn_s_barrier();
  __builtin_amdgcn_sched_barrier(0);
  int cur = 0;

#pragma unroll 1
  for (int t = 0; t < nst; ++t) {
    const int tn = t + 1;
    // prefetch next stage into the other buffer. Safe with ONE barrier/stage:
    // buf[cur^1]'s readers (stage t-1) retired their ds_reads before the
    // barrier we crossed at the end of stage t-1.
    if (tn < nst) issue_stage(tn, cur ^ 1);

    const unsigned short* bq = &sQ[cur][0];
    const unsigned short* bs = &sS[cur][0];
    __builtin_amdgcn_s_setprio(1);
#pragma unroll
    for (int kk = 0; kk < 2; ++kk) {
      const int koff = ((kk * 4 + quad) ^ c7) * 8;
      bf16x8 asv[8];
#pragma unroll
      for (int st = 0; st < 8; ++st)
        asv[st] = *(const bf16x8*)&bs[(h * 128 + st * 16 + col) * BK + koff];
#pragma unroll
      for (int qt = 0; qt < 4; ++qt) {
        bf16x8 aq = *(const bf16x8*)&bq[(g * 64 + qt * 16 + col) * BK + koff];
#pragma unroll
        for (int st = 0; st < 8; ++st)
          acc[st][qt] = __builtin_amdgcn_mfma_f32_16x16x32_bf16(asv[st], aq, acc[st][qt], 0, 0, 0);
      }
    }
    __builtin_amdgcn_s_setprio(0);

    // stage t+1 fully landed (issued a full MFMA phase ago) + all waves done
    // reading buf[cur] -> one sync point per stage.
    asm volatile("s_waitcnt vmcnt(0)" ::: "memory");
    __builtin_amdgcn_s_barrier();
    __builtin_amdgcn_sched_barrier(0);
    cur ^= 1;

    if ((t & (NKC - 1)) == NKC - 1) {
      // online softmax-weighted-mean update over this wave's 128-s rows
#pragma unroll
      for (int qt = 0; qt < 4; ++qt) {
        float lmax = mst[qt];
#pragma unroll
        for (int st = 0; st < 8; ++st)
#pragma unroll
          for (int r = 0; r < 4; ++r)
            lmax = fmaxf(lmax, acc[st][qt][r]);
        lmax = fmaxf(lmax, __shfl_xor(lmax, 16, 64));
        lmax = fmaxf(lmax, __shfl_xor(lmax, 32, 64));
        float alpha = __expf(mst[qt] - lmax);  // exp(-inf)=0 on first block
        float pe = 0.f, pel = 0.f;
#pragma unroll
        for (int st = 0; st < 8; ++st)
#pragma unroll
          for (int r = 0; r < 4; ++r) {
            float l = acc[st][qt][r];
            float e = __expf(l - lmax);
            pe += e;
            pel = fmaf(e, l, pel);
          }
        pe  += __shfl_xor(pe, 16, 64);  pe  += __shfl_xor(pe, 32, 64);
        pel += __shfl_xor(pel, 16, 64); pel += __shfl_xor(pel, 32, 64);
        se[qt]  = fmaf(se[qt],  alpha, pe);
        sel[qt] = fmaf(sel[qt], alpha, pel);
        mst[qt] = lmax;
#pragma unroll
        for (int st = 0; st < 8; ++st)
          acc[st][qt] = (f32x4){0.f, 0.f, 0.f, 0.f};
      }
    }
  }

  // merge the two s-halves (h=0,1) per q-column via LDS, then write
  __syncthreads();
  float* red = (float*)&sQ[0][0];   // 3*512 floats = 6 KiB, sQ no longer needed
  if (quad == 0) {
#pragma unroll
    for (int qt = 0; qt < 4; ++qt) {
      int qq = g * 64 + qt * 16 + col;
      red[h * 256 + qq]        = mst[qt];
      red[512 + h * 256 + qq]  = se[qt];
      red[1024 + h * 256 + qq] = sel[qt];
    }
  }
  __syncthreads();
  if (h == 0 && quad == 0) {
#pragma unroll
    for (int qt = 0; qt < 4; ++qt) {
      int qq = g * 64 + qt * 16 + col;
      float m0 = red[qq],       m1 = red[256 + qq];
      float M  = fmaxf(m0, m1);
      float a0 = __expf(m0 - M), a1 = __expf(m1 - M);
      float SE  = red[512 + qq]  * a0 + red[512 + 256 + qq]  * a1;
      float SEL = red[1024 + qq] * a0 + red[1024 + 256 + qq] * a1;
      size_t qi = (size_t)b * LQ + q0 + qq;
      if (nsplit == 1) {
        out[qi] = SEL / SE;
      } else {
        pm[qi * NSPLIT + spl]   = M;
        pse[qi * NSPLIT + spl]  = SE;
        psel[qi * NSPLIT + spl] = SEL;
      }
    }
  }
}

__global__ __launch_bounds__(256) void combine_kernel(const float* __restrict__ pm,
                                                      const float* __restrict__ pse,
                                                      const float* __restrict__ psel,
                                                      float* __restrict__ out) {
  int i = blockIdx.x * blockDim.x + threadIdx.x;
  if (i >= B_ * LQ) return;
  float M = -INFINITY;
#pragma unroll
  for (int s = 0; s < NSPLIT; ++s) M = fmaxf(M, pm[i * NSPLIT + s]);
  float SE = 0.f, SEL = 0.f;
#pragma unroll
  for (int s = 0; s < NSPLIT; ++s) {
    float a = __expf(pm[i * NSPLIT + s] - M);
    SE  = fmaf(pse[i * NSPLIT + s],  a, SE);
    SEL = fmaf(psel[i * NSPLIT + s], a, SEL);
  }
  out[i] = SEL / SE;
}

// fp32 fallback (correctness insurance if ws too small)
__global__ __launch_bounds__(256) void fallback_kernel(const float* __restrict__ Q,
                                                       const float* __restrict__ S,
                                                       float* __restrict__ out) {
  __shared__ float qv[DD];
  __shared__ float red[256];
  const int b = blockIdx.y, qi = blockIdx.x, tid = threadIdx.x;
  const float* qrow = Q + ((size_t)b * LQ + qi) * DD;
  for (int d = tid; d < DD; d += 256) qv[d] = qrow[d];
  __syncthreads();
  const float* Sb = S + (size_t)b * LS * DD;
  float m = -INFINITY, se = 0.f, sel = 0.f;
  for (int s = tid; s < LS; s += 256) {
    const float* srow = Sb + (size_t)s * DD;
    float dot = 0.f;
    for (int d = 0; d < DD; ++d) dot = fmaf(qv[d], srow[d], dot);
    float mn = fmaxf(m, dot);
    float a = __expf(m - mn);
    float e = __expf(dot - mn);
    se  = se * a + e;
    sel = sel * a + e * dot;
    m = mn;
  }
  red[tid] = m; __syncthreads();
  for (int o = 128; o > 0; o >>= 1) { if (tid < o) red[tid] = fmaxf(red[tid], red[tid + o]); __syncthreads(); }
  float M = red[0]; __syncthreads();
  float a = __expf(m - M); se *= a; sel *= a;
  red[tid] = se; __syncthreads();
  for (int o = 128; o > 0; o >>= 1) { if (tid < o) red[tid] += red[tid + o]; __syncthreads(); }
  float SE = red[0]; __syncthreads();
  red[tid] = sel; __syncthreads();
  for (int o = 128; o > 0; o >>= 1) { if (tid < o) red[tid] += red[tid + o]; __syncthreads(); }
  float SEL = red[0];
  if (tid == 0) out[(size_t)b * LQ + qi] = SEL / SE;
}

extern "C" void kernel_launch(void* const* d_in, const int* in_sizes, int n_in,
                              void* d_out, int out_size, void* d_ws, size_t ws_size,
                              hipStream_t stream) {
  const float* Q = (const float*)d_in[0];
  const float* S = (const float*)d_in[1];
  float* out = (float*)d_out;
  const size_t nelem = (size_t)B_ * LQ * DD;                    // 16.78M / tensor
  const size_t need_base  = 2 * nelem * sizeof(unsigned short); // 67 MiB
  const size_t part_elems = (size_t)B_ * LQ * NSPLIT;
  const size_t need_split = need_base + 3 * part_elems * sizeof(float);

  if (ws_size >= need_base) {
    unsigned short* Qw = (unsigned short*)d_ws;
    unsigned short* Sw = Qw + nelem;
    cvt_kernel<<<2048, 256, 0, stream>>>(Q, S, Qw, Sw);
    if (ws_size >= need_split) {
      float* pm   = (float*)(Sw + nelem);
      float* pse  = pm + part_elems;
      float* psel = pse + part_elems;
      attn_kernel<<<dim3(LQ / BQ, B_, NSPLIT), 512, 0, stream>>>(Qw, Sw, out, pm, pse, psel, NSPLIT);
      combine_kernel<<<(B_ * LQ + 255) / 256, 256, 0, stream>>>(pm, pse, psel, out);
    } else {
      attn_kernel<<<dim3(LQ / BQ, B_, 1), 512, 0, stream>>>(Qw, Sw, out, nullptr, nullptr, nullptr, 1);
    }
  } else {
    fallback_kernel<<<dim3(LQ, B_), 256, 0, stream>>>(Q, S, out);
  }
}